// Round 13
// baseline (2369.267 us; speedup 1.0000x reference)
//
#include <hip/hip_runtime.h>
#include <hip/hip_fp16.h>

#define NN 100000
#define HD 64
#define NB ((NN + 255) >> 8)   // 391 dst-buckets of 256 nodes
#define P1_CHUNK 8192
#define PSTR 100352             // plane stride in 16B (float4) units

// k1: per-chunk LDS histogram of dst>>8 -> global bucket counts
__global__ __launch_bounds__(256) void hist_kernel(const int* __restrict__ dst,
                                                   int* __restrict__ bcnt, int E) {
    __shared__ int hist[NB];
    int t = threadIdx.x;
    int e0 = blockIdx.x * P1_CHUNK;
    int count = min(P1_CHUNK, E - e0);
    for (int b = t; b < NB; b += 256) hist[b] = 0;
    __syncthreads();
    for (int i = t; i < count; i += 256) atomicAdd(&hist[dst[e0 + i] >> 8], 1);
    __syncthreads();
    for (int b = t; b < NB; b += 256) {
        int c = hist[b];
        if (c) atomicAdd(&bcnt[b], c);
    }
}

// k2: single block scan of NB bucket counts -> boff (exclusive), bcur copy
__global__ void bscan_kernel(const int* __restrict__ bcnt, int* __restrict__ boff,
                             int* __restrict__ bcur, int E) {
    __shared__ int sm[512];
    int t = threadIdx.x;
    int v = (t < NB) ? bcnt[t] : 0;
    sm[t] = v;
    __syncthreads();
    for (int off = 1; off < 512; off <<= 1) {
        int u = (t >= off) ? sm[t - off] : 0;
        __syncthreads();
        sm[t] += u;
        __syncthreads();
    }
    if (t < NB) {
        boff[t] = sm[t] - v;
        bcur[t] = sm[t] - v;
    }
    if (t == 0) boff[NB] = E;
}

// k3: chunked bucket scatter — ebuf entry packed: (d & 255) << 24 | src
__global__ __launch_bounds__(256) void p1_kernel(const int* __restrict__ src,
                                                 const int* __restrict__ dst,
                                                 int* __restrict__ bcur,
                                                 unsigned* __restrict__ ebuf, int E) {
    __shared__ int hist[NB];
    __shared__ int cur[NB];
    int t = threadIdx.x;
    int e0 = blockIdx.x * P1_CHUNK;
    int count = min(P1_CHUNK, E - e0);
    for (int b = t; b < NB; b += 256) hist[b] = 0;
    __syncthreads();
    for (int i = t; i < count; i += 256) atomicAdd(&hist[dst[e0 + i] >> 8], 1);
    __syncthreads();
    for (int b = t; b < NB; b += 256) {
        int c = hist[b];
        cur[b] = c ? atomicAdd(&bcur[b], c) : 0;
    }
    __syncthreads();
    for (int i = t; i < count; i += 256) {
        int d = dst[e0 + i], s = src[e0 + i];
        int pos = atomicAdd(&cur[d >> 8], 1);
        ebuf[pos] = ((unsigned)(d & 255) << 24) | (unsigned)s;
    }
}

// k4: one block per bucket — LDS degree count -> dinv only (no CSR needed anymore)
__global__ __launch_bounds__(256) void p2_kernel(const unsigned* __restrict__ ebuf,
                                                 const int* __restrict__ boff,
                                                 float* __restrict__ dinv, int n) {
    __shared__ int cnt[256];
    int b = blockIdx.x;
    int node0 = b << 8;
    int t = threadIdx.x;
    cnt[t] = 0;
    __syncthreads();
    int beg = boff[b], end = boff[b + 1];
    for (int i = beg + t; i < end; i += 256) atomicAdd(&cnt[ebuf[i] >> 24], 1);
    __syncthreads();
    int node = node0 + t;
    if (node < n) dinv[node] = rsqrtf((float)cnt[t] + 1.0f);   // +1 = self loop
}

// H(fp16, 8 slice-planes) = (X @ W) * dinv[row] — 64x64 tile/block, 4x4 micro-tile.
// X fp32 contiguous (layer 0) or fp16 slice-planes (layers 1..3).
__global__ __launch_bounds__(256) void matmul64_kernel(const void* __restrict__ Xv,
                                                       int x_is_half,
                                                       const float* __restrict__ W,
                                                       const float* __restrict__ dinv,
                                                       float4* __restrict__ H, int n) {
    __shared__ float Wl[64 * 64];      // [k][c]
    __shared__ float Xs[64 * 65];      // [r][k], padded
    int tid = threadIdx.x;
    int row0 = blockIdx.x * 64;
    const float4* W4 = (const float4*)W;
    float4* Wl4 = (float4*)Wl;
#pragma unroll
    for (int i = 0; i < 4; ++i) Wl4[tid + 256 * i] = W4[tid + 256 * i];
    if (x_is_half) {
        const float4* X4 = (const float4*)Xv;   // 8 planes of fp16x8
#pragma unroll
        for (int i = 0; i < 2; ++i) {
            int l = tid + 256 * i;              // 512 = 64 rows x 8 planes
            int r = l >> 3, p = l & 7;
            int row = row0 + r;
            float4 xv = (row < n) ? X4[(size_t)p * PSTR + row]
                                  : make_float4(0.f, 0.f, 0.f, 0.f);
            const __half2* hp = (const __half2*)&xv;
#pragma unroll
            for (int j = 0; j < 4; ++j) {
                float2 f = __half22float2(hp[j]);
                Xs[r * 65 + p * 8 + 2 * j]     = f.x;
                Xs[r * 65 + p * 8 + 2 * j + 1] = f.y;
            }
        }
    } else {
        const float4* X4 = (const float4*)Xv;
#pragma unroll
        for (int i = 0; i < 4; ++i) {
            int l = tid + 256 * i;              // 1024 = 64 rows x 16
            int r = l >> 4, k0 = (l & 15) * 4;
            int row = row0 + r;
            float4 xv = (row < n) ? X4[(size_t)row * 16 + (l & 15)]
                                  : make_float4(0.f, 0.f, 0.f, 0.f);
            Xs[r * 65 + k0 + 0] = xv.x;
            Xs[r * 65 + k0 + 1] = xv.y;
            Xs[r * 65 + k0 + 2] = xv.z;
            Xs[r * 65 + k0 + 3] = xv.w;
        }
    }
    __syncthreads();
    int tx = tid & 15, ty = tid >> 4;   // cols c0=4*tx, rows r0=4*ty
    float acc[4][4] = {};
    const float4* Wlr4 = (const float4*)Wl;
#pragma unroll 4
    for (int k = 0; k < 64; ++k) {
        float4 b = Wlr4[k * 16 + tx];
        float a0 = Xs[(ty * 4 + 0) * 65 + k];
        float a1 = Xs[(ty * 4 + 1) * 65 + k];
        float a2 = Xs[(ty * 4 + 2) * 65 + k];
        float a3 = Xs[(ty * 4 + 3) * 65 + k];
        acc[0][0] += a0 * b.x; acc[0][1] += a0 * b.y; acc[0][2] += a0 * b.z; acc[0][3] += a0 * b.w;
        acc[1][0] += a1 * b.x; acc[1][1] += a1 * b.y; acc[1][2] += a1 * b.z; acc[1][3] += a1 * b.w;
        acc[2][0] += a2 * b.x; acc[2][1] += a2 * b.y; acc[2][2] += a2 * b.z; acc[2][3] += a2 * b.w;
        acc[3][0] += a3 * b.x; acc[3][1] += a3 * b.y; acc[3][2] += a3 * b.z; acc[3][3] += a3 * b.w;
    }
    int p = tx >> 1, halfsel = tx & 1;  // plane, 8B half of the 16B slice
#pragma unroll
    for (int j = 0; j < 4; ++j) {
        int row = row0 + ty * 4 + j;
        if (row < n) {
            float dn = dinv[row];
            __half2 p01 = __float22half2_rn(make_float2(acc[j][0] * dn, acc[j][1] * dn));
            __half2 p23 = __float22half2_rn(make_float2(acc[j][2] * dn, acc[j][3] * dn));
            float2 st;
            st.x = *reinterpret_cast<float*>(&p01);
            st.y = *reinterpret_cast<float*>(&p23);
            ((float2*)H)[((size_t)p * PSTR + row) * 2 + halfsel] = st;
        }
    }
}

// agg: one block per (bucket, slice); slice = blockIdx & 7 for XCD-L2 affinity.
// LDS fp32 accumulators [256 nodes][8 ch]; edges from packed ebuf; fp16 plane I/O.
__global__ __launch_bounds__(256) void agg_kernel(const float4* __restrict__ h,
                                                  const unsigned* __restrict__ ebuf,
                                                  const int* __restrict__ boff,
                                                  const float* __restrict__ dinv,
                                                  const float* __restrict__ b,
                                                  const float4* __restrict__ xprev,
                                                  float4* __restrict__ xout,
                                                  int n, int residual) {
    __shared__ float acc[256][9];   // pad 9 to spread banks
    int blk = blockIdx.x;
    int s = blk & 7, bkt = blk >> 3;
    int node0 = bkt << 8;
    int t = threadIdx.x;
#pragma unroll
    for (int c = 0; c < 8; ++c) acc[t][c] = 0.f;
    __syncthreads();
    int beg = boff[bkt], end = boff[bkt + 1];
    const float4* hp = h + (size_t)s * PSTR;
    for (int i = beg + t; i < end; i += 256) {
        unsigned u = ebuf[i];
        int d = u >> 24;
        int sr = (int)(u & 0xFFFFFFu);
        float4 v = hp[sr];
        const __half2* q = (const __half2*)&v;
        float2 f0 = __half22float2(q[0]);
        float2 f1 = __half22float2(q[1]);
        float2 f2 = __half22float2(q[2]);
        float2 f3 = __half22float2(q[3]);
        atomicAdd(&acc[d][0], f0.x); atomicAdd(&acc[d][1], f0.y);
        atomicAdd(&acc[d][2], f1.x); atomicAdd(&acc[d][3], f1.y);
        atomicAdd(&acc[d][4], f2.x); atomicAdd(&acc[d][5], f2.y);
        atomicAdd(&acc[d][6], f3.x); atomicAdd(&acc[d][7], f3.y);
    }
    __syncthreads();
    int node = node0 + t;
    if (node < n) {
        float dn = dinv[node];
        float4 sv = hp[node];  // self loop (pre-scaled by dinv[src])
        const __half2* q = (const __half2*)&sv;
        float2 s0 = __half22float2(q[0]);
        float2 s1 = __half22float2(q[1]);
        float2 s2 = __half22float2(q[2]);
        float2 s3 = __half22float2(q[3]);
        float vch[8];
        vch[0] = (acc[t][0] + s0.x) * dn + b[s * 8 + 0];
        vch[1] = (acc[t][1] + s0.y) * dn + b[s * 8 + 1];
        vch[2] = (acc[t][2] + s1.x) * dn + b[s * 8 + 2];
        vch[3] = (acc[t][3] + s1.y) * dn + b[s * 8 + 3];
        vch[4] = (acc[t][4] + s2.x) * dn + b[s * 8 + 4];
        vch[5] = (acc[t][5] + s2.y) * dn + b[s * 8 + 5];
        vch[6] = (acc[t][6] + s3.x) * dn + b[s * 8 + 6];
        vch[7] = (acc[t][7] + s3.y) * dn + b[s * 8 + 7];
        if (residual) {
            float4 rr = xprev[(size_t)s * PSTR + node];
            const __half2* rp = (const __half2*)&rr;
            float2 r0 = __half22float2(rp[0]);
            float2 r1 = __half22float2(rp[1]);
            float2 r2 = __half22float2(rp[2]);
            float2 r3 = __half22float2(rp[3]);
            vch[0] += r0.x; vch[1] += r0.y; vch[2] += r1.x; vch[3] += r1.y;
            vch[4] += r2.x; vch[5] += r2.y; vch[6] += r3.x; vch[7] += r3.y;
        }
#pragma unroll
        for (int c = 0; c < 8; ++c) vch[c] = fmaxf(vch[c], 0.f);
        __half2 o0 = __float22half2_rn(make_float2(vch[0], vch[1]));
        __half2 o1 = __float22half2_rn(make_float2(vch[2], vch[3]));
        __half2 o2 = __float22half2_rn(make_float2(vch[4], vch[5]));
        __half2 o3 = __float22half2_rn(make_float2(vch[6], vch[7]));
        float4 st;
        st.x = *reinterpret_cast<float*>(&o0);
        st.y = *reinterpret_cast<float*>(&o1);
        st.z = *reinterpret_cast<float*>(&o2);
        st.w = *reinterpret_cast<float*>(&o3);
        xout[(size_t)s * PSTR + node] = st;
    }
}

// final 64->3 projection from sliced fp16 activations
__global__ __launch_bounds__(256) void proj_kernel(const float4* __restrict__ xc,
                                                   const float* __restrict__ Wc,
                                                   const float* __restrict__ bc,
                                                   float* __restrict__ out, int n) {
    __shared__ float Wl[192];
    int t = threadIdx.x;
    if (t < 192) Wl[t] = Wc[t];
    __syncthreads();
    int node = blockIdx.x * 256 + t;
    if (node >= n) return;
    float p0 = bc[0], p1 = bc[1], p2 = bc[2];
#pragma unroll
    for (int s = 0; s < 8; ++s) {
        float4 v = xc[(size_t)s * PSTR + node];
        const __half2* q = (const __half2*)&v;
#pragma unroll
        for (int j = 0; j < 4; ++j) {
            float2 f = __half22float2(q[j]);
            int ch = s * 8 + j * 2;
            p0 += f.x * Wl[ch * 3 + 0] + f.y * Wl[(ch + 1) * 3 + 0];
            p1 += f.x * Wl[ch * 3 + 1] + f.y * Wl[(ch + 1) * 3 + 1];
            p2 += f.x * Wl[ch * 3 + 2] + f.y * Wl[(ch + 1) * 3 + 2];
        }
    }
    out[node * 3 + 0] = p0;
    out[node * 3 + 1] = p1;
    out[node * 3 + 2] = p2;
}

extern "C" void kernel_launch(void* const* d_in, const int* in_sizes, int n_in,
                              void* d_out, int out_size, void* d_ws, size_t ws_size,
                              hipStream_t stream) {
    const float* x  = (const float*)d_in[0];
    const int*   ei = (const int*)d_in[1];
    const float* Ws = (const float*)d_in[2];
    const float* bs = (const float*)d_in[3];
    const float* Wc = (const float*)d_in[4];
    const float* bc = (const float*)d_in[5];
    float* out = (float*)d_out;

    int E = in_sizes[1] / 2;
    const int* src = ei;
    const int* dst = ei + E;
    int nchunks = (E + P1_CHUNK - 1) / P1_CHUNK;

    char* wsb = (char*)d_ws;
    size_t off = 0;
    int*      bcnt = (int*)(wsb + off); off += 512 * 4;
    int*      boff = (int*)(wsb + off); off += 512 * 4;
    int*      bcur = (int*)(wsb + off); off += 512 * 4;
    float*    dinv = (float*)(wsb + off); off += 100352 * 4;
    unsigned* ebuf = (unsigned*)(wsb + off); off += (size_t)E * 4;
    float4*   h    = (float4*)(wsb + off); off += (size_t)8 * PSTR * 16;  // sliced fp16 h
    float4*   xa   = (float4*)(wsb + off); off += (size_t)8 * PSTR * 16;  // sliced fp16 acts
    float4*   xb   = (float4*)(wsb + off); off += (size_t)8 * PSTR * 16;

    // graph build: bucket counts -> offsets -> packed bucketed pairs -> dinv
    hipMemsetAsync(bcnt, 0, 512 * sizeof(int), stream);
    hist_kernel<<<nchunks, 256, 0, stream>>>(dst, bcnt, E);
    bscan_kernel<<<1, 512, 0, stream>>>(bcnt, boff, bcur, E);
    p1_kernel<<<nchunks, 256, 0, stream>>>(src, dst, bcur, ebuf, E);
    p2_kernel<<<NB, 256, 0, stream>>>(ebuf, boff, dinv, NN);

    // layers (ping-pong sliced fp16 xa/xb)
    const void* xin = (const void*)x;
    int xin_half = 0;
    float4* bufs[2] = {xa, xb};
    for (int l = 0; l < 4; ++l) {
        float4* xout = bufs[l & 1];
        matmul64_kernel<<<(NN + 63) / 64, 256, 0, stream>>>(
            xin, xin_half, Ws + (size_t)l * HD * HD, dinv, h, NN);
        agg_kernel<<<NB * 8, 256, 0, stream>>>(
            h, ebuf, boff, dinv, bs + l * HD, (const float4*)xin, xout, NN, l > 0);
        xin = (const void*)xout;
        xin_half = 1;
    }
    proj_kernel<<<(NN + 255) / 256, 256, 0, stream>>>(bufs[1], Wc, bc, out, NN);
}

// Round 14
// 492.116 us; speedup vs baseline: 4.8144x; 4.8144x over previous
//
#include <hip/hip_runtime.h>
#include <hip/hip_fp16.h>

#define NN 100000
#define HD 64
#define NB ((NN + 255) >> 8)   // 391 dst-buckets of 256 nodes
#define P1_CHUNK 8192
#define PSTR 100352             // plane stride in 16B (float4) units

// k1: per-chunk LDS histogram of dst>>8 -> global bucket counts
__global__ __launch_bounds__(256) void hist_kernel(const int* __restrict__ dst,
                                                   int* __restrict__ bcnt, int E) {
    __shared__ int hist[NB];
    int t = threadIdx.x;
    int e0 = blockIdx.x * P1_CHUNK;
    int count = min(P1_CHUNK, E - e0);
    for (int b = t; b < NB; b += 256) hist[b] = 0;
    __syncthreads();
    for (int i = t; i < count; i += 256) atomicAdd(&hist[dst[e0 + i] >> 8], 1);
    __syncthreads();
    for (int b = t; b < NB; b += 256) {
        int c = hist[b];
        if (c) atomicAdd(&bcnt[b], c);
    }
}

// k2: single block scan of NB bucket counts -> boff (exclusive), bcur copy
__global__ void bscan_kernel(const int* __restrict__ bcnt, int* __restrict__ boff,
                             int* __restrict__ bcur, int* __restrict__ row_ptr,
                             int E, int n) {
    __shared__ int sm[512];
    int t = threadIdx.x;
    int v = (t < NB) ? bcnt[t] : 0;
    sm[t] = v;
    __syncthreads();
    for (int off = 1; off < 512; off <<= 1) {
        int u = (t >= off) ? sm[t - off] : 0;
        __syncthreads();
        sm[t] += u;
        __syncthreads();
    }
    if (t < NB) {
        boff[t] = sm[t] - v;
        bcur[t] = sm[t] - v;
    }
    if (t == 0) {
        boff[NB] = E;
        row_ptr[n] = E;
    }
}

// k3: chunked bucket scatter — ebuf entry packed: (d & 255) << 24 | src
__global__ __launch_bounds__(256) void p1_kernel(const int* __restrict__ src,
                                                 const int* __restrict__ dst,
                                                 int* __restrict__ bcur,
                                                 unsigned* __restrict__ ebuf, int E) {
    __shared__ int hist[NB];
    __shared__ int cur[NB];
    int t = threadIdx.x;
    int e0 = blockIdx.x * P1_CHUNK;
    int count = min(P1_CHUNK, E - e0);
    for (int b = t; b < NB; b += 256) hist[b] = 0;
    __syncthreads();
    for (int i = t; i < count; i += 256) atomicAdd(&hist[dst[e0 + i] >> 8], 1);
    __syncthreads();
    for (int b = t; b < NB; b += 256) {
        int c = hist[b];
        cur[b] = c ? atomicAdd(&bcur[b], c) : 0;
    }
    __syncthreads();
    for (int i = t; i < count; i += 256) {
        int d = dst[e0 + i], s = src[e0 + i];
        int pos = atomicAdd(&cur[d >> 8], 1);
        ebuf[pos] = ((unsigned)(d & 255) << 24) | (unsigned)s;
    }
}

// k4: one block per bucket — LDS degree count + scan -> row_ptr/dinv, then local CSR scatter
__global__ __launch_bounds__(256) void p2_kernel(const unsigned* __restrict__ ebuf,
                                                 const int* __restrict__ boff,
                                                 int* __restrict__ row_ptr,
                                                 float* __restrict__ dinv,
                                                 int* __restrict__ csr_src, int n) {
    __shared__ int cnt[256];
    __shared__ int cur[256];
    int b = blockIdx.x;
    int node0 = b << 8;
    int t = threadIdx.x;
    int beg = boff[b], end = boff[b + 1];
    cnt[t] = 0;
    __syncthreads();
    for (int i = beg + t; i < end; i += 256) atomicAdd(&cnt[ebuf[i] >> 24], 1);
    __syncthreads();
    int deg = cnt[t];
    for (int off = 1; off < 256; off <<= 1) {   // inclusive scan
        int v = (t >= off) ? cnt[t - off] : 0;
        __syncthreads();
        cnt[t] += v;
        __syncthreads();
    }
    int excl = cnt[t] - deg;
    int node = node0 + t;
    if (node < n) {
        row_ptr[node] = beg + excl;
        dinv[node] = rsqrtf((float)deg + 1.0f);   // +1 = self loop
    }
    cur[t] = beg + excl;
    __syncthreads();
    for (int i = beg + t; i < end; i += 256) {
        unsigned p = ebuf[i];
        int pos = atomicAdd(&cur[p >> 24], 1);
        csr_src[pos] = (int)(p & 0xFFFFFFu);
    }
}

// H(fp16, 8 slice-planes) = (X @ W) * dinv[row] — 64x64 tile/block, 4x4 micro-tile.
__global__ __launch_bounds__(256) void matmul64_kernel(const void* __restrict__ Xv,
                                                       int x_is_half,
                                                       const float* __restrict__ W,
                                                       const float* __restrict__ dinv,
                                                       float4* __restrict__ H, int n) {
    __shared__ float Wl[64 * 64];      // [k][c]
    __shared__ float Xs[64 * 65];      // [r][k], padded
    int tid = threadIdx.x;
    int row0 = blockIdx.x * 64;
    const float4* W4 = (const float4*)W;
    float4* Wl4 = (float4*)Wl;
#pragma unroll
    for (int i = 0; i < 4; ++i) Wl4[tid + 256 * i] = W4[tid + 256 * i];
    if (x_is_half) {
        const float4* X4 = (const float4*)Xv;   // 8 planes of fp16x8
#pragma unroll
        for (int i = 0; i < 2; ++i) {
            int l = tid + 256 * i;              // 512 = 64 rows x 8 planes
            int r = l >> 3, p = l & 7;
            int row = row0 + r;
            float4 xv = (row < n) ? X4[(size_t)p * PSTR + row]
                                  : make_float4(0.f, 0.f, 0.f, 0.f);
            const __half2* hp = (const __half2*)&xv;
#pragma unroll
            for (int j = 0; j < 4; ++j) {
                float2 f = __half22float2(hp[j]);
                Xs[r * 65 + p * 8 + 2 * j]     = f.x;
                Xs[r * 65 + p * 8 + 2 * j + 1] = f.y;
            }
        }
    } else {
        const float4* X4 = (const float4*)Xv;
#pragma unroll
        for (int i = 0; i < 4; ++i) {
            int l = tid + 256 * i;              // 1024 = 64 rows x 16
            int r = l >> 4, k0 = (l & 15) * 4;
            int row = row0 + r;
            float4 xv = (row < n) ? X4[(size_t)row * 16 + (l & 15)]
                                  : make_float4(0.f, 0.f, 0.f, 0.f);
            Xs[r * 65 + k0 + 0] = xv.x;
            Xs[r * 65 + k0 + 1] = xv.y;
            Xs[r * 65 + k0 + 2] = xv.z;
            Xs[r * 65 + k0 + 3] = xv.w;
        }
    }
    __syncthreads();
    int tx = tid & 15, ty = tid >> 4;   // cols c0=4*tx, rows r0=4*ty
    float acc[4][4] = {};
    const float4* Wlr4 = (const float4*)Wl;
#pragma unroll 4
    for (int k = 0; k < 64; ++k) {
        float4 b = Wlr4[k * 16 + tx];
        float a0 = Xs[(ty * 4 + 0) * 65 + k];
        float a1 = Xs[(ty * 4 + 1) * 65 + k];
        float a2 = Xs[(ty * 4 + 2) * 65 + k];
        float a3 = Xs[(ty * 4 + 3) * 65 + k];
        acc[0][0] += a0 * b.x; acc[0][1] += a0 * b.y; acc[0][2] += a0 * b.z; acc[0][3] += a0 * b.w;
        acc[1][0] += a1 * b.x; acc[1][1] += a1 * b.y; acc[1][2] += a1 * b.z; acc[1][3] += a1 * b.w;
        acc[2][0] += a2 * b.x; acc[2][1] += a2 * b.y; acc[2][2] += a2 * b.z; acc[2][3] += a2 * b.w;
        acc[3][0] += a3 * b.x; acc[3][1] += a3 * b.y; acc[3][2] += a3 * b.z; acc[3][3] += a3 * b.w;
    }
    int p = tx >> 1, halfsel = tx & 1;  // plane, 8B half of the 16B slice
#pragma unroll
    for (int j = 0; j < 4; ++j) {
        int row = row0 + ty * 4 + j;
        if (row < n) {
            float dn = dinv[row];
            __half2 p01 = __float22half2_rn(make_float2(acc[j][0] * dn, acc[j][1] * dn));
            __half2 p23 = __float22half2_rn(make_float2(acc[j][2] * dn, acc[j][3] * dn));
            float2 st;
            st.x = *reinterpret_cast<float*>(&p01);
            st.y = *reinterpret_cast<float*>(&p23);
            ((float2*)H)[((size_t)p * PSTR + row) * 2 + halfsel] = st;
        }
    }
}

#define UNP_ADD(V) do {                                                      \
    const __half2* _q = (const __half2*)&(V);                                \
    float2 _f0 = __half22float2(_q[0]);                                      \
    float2 _f1 = __half22float2(_q[1]);                                      \
    float2 _f2 = __half22float2(_q[2]);                                      \
    float2 _f3 = __half22float2(_q[3]);                                      \
    a[0] += _f0.x; a[1] += _f0.y; a[2] += _f1.x; a[3] += _f1.y;              \
    a[4] += _f2.x; a[5] += _f2.y; a[6] += _f3.x; a[7] += _f3.y;              \
} while (0)

// agg: one THREAD per (node, slice); slice = blockIdx & 7 for XCD-L2 affinity.
// Sequential CSR edge loop, 4-way unrolled gathers, fp32 register accumulation.
__global__ __launch_bounds__(256) void agg_kernel(const float4* __restrict__ h,
                                                  const int* __restrict__ row_ptr,
                                                  const int* __restrict__ csr_src,
                                                  const float* __restrict__ dinv,
                                                  const float* __restrict__ b,
                                                  const float4* __restrict__ xprev,
                                                  float4* __restrict__ xout,
                                                  int n, int residual) {
    int s = blockIdx.x & 7;
    int node = (blockIdx.x >> 3) * 256 + threadIdx.x;
    if (node >= n) return;
    const float4* hp = h + (size_t)s * PSTR;
    int beg = row_ptr[node], end = row_ptr[node + 1];
    float a[8] = {0.f, 0.f, 0.f, 0.f, 0.f, 0.f, 0.f, 0.f};
    int p = beg;
    for (; p + 4 <= end; p += 4) {
        int s0 = csr_src[p + 0];
        int s1 = csr_src[p + 1];
        int s2 = csr_src[p + 2];
        int s3 = csr_src[p + 3];
        float4 v0 = hp[s0];
        float4 v1 = hp[s1];
        float4 v2 = hp[s2];
        float4 v3 = hp[s3];
        UNP_ADD(v0); UNP_ADD(v1); UNP_ADD(v2); UNP_ADD(v3);
    }
    for (; p < end; ++p) {
        float4 v = hp[csr_src[p]];
        UNP_ADD(v);
    }
    {
        float4 sv = hp[node];   // self loop (pre-scaled by dinv[src])
        UNP_ADD(sv);
    }
    float dn = dinv[node];
    float vch[8];
#pragma unroll
    for (int c = 0; c < 8; ++c) vch[c] = a[c] * dn + b[s * 8 + c];
    if (residual) {
        float4 rr = xprev[(size_t)s * PSTR + node];
        const __half2* rp = (const __half2*)&rr;
        float2 r0 = __half22float2(rp[0]);
        float2 r1 = __half22float2(rp[1]);
        float2 r2 = __half22float2(rp[2]);
        float2 r3 = __half22float2(rp[3]);
        vch[0] += r0.x; vch[1] += r0.y; vch[2] += r1.x; vch[3] += r1.y;
        vch[4] += r2.x; vch[5] += r2.y; vch[6] += r3.x; vch[7] += r3.y;
    }
#pragma unroll
    for (int c = 0; c < 8; ++c) vch[c] = fmaxf(vch[c], 0.f);
    __half2 o0 = __float22half2_rn(make_float2(vch[0], vch[1]));
    __half2 o1 = __float22half2_rn(make_float2(vch[2], vch[3]));
    __half2 o2 = __float22half2_rn(make_float2(vch[4], vch[5]));
    __half2 o3 = __float22half2_rn(make_float2(vch[6], vch[7]));
    float4 st;
    st.x = *reinterpret_cast<float*>(&o0);
    st.y = *reinterpret_cast<float*>(&o1);
    st.z = *reinterpret_cast<float*>(&o2);
    st.w = *reinterpret_cast<float*>(&o3);
    xout[(size_t)s * PSTR + node] = st;
}

// final 64->3 projection from sliced fp16 activations
__global__ __launch_bounds__(256) void proj_kernel(const float4* __restrict__ xc,
                                                   const float* __restrict__ Wc,
                                                   const float* __restrict__ bc,
                                                   float* __restrict__ out, int n) {
    __shared__ float Wl[192];
    int t = threadIdx.x;
    if (t < 192) Wl[t] = Wc[t];
    __syncthreads();
    int node = blockIdx.x * 256 + t;
    if (node >= n) return;
    float p0 = bc[0], p1 = bc[1], p2 = bc[2];
#pragma unroll
    for (int s = 0; s < 8; ++s) {
        float4 v = xc[(size_t)s * PSTR + node];
        const __half2* q = (const __half2*)&v;
#pragma unroll
        for (int j = 0; j < 4; ++j) {
            float2 f = __half22float2(q[j]);
            int ch = s * 8 + j * 2;
            p0 += f.x * Wl[ch * 3 + 0] + f.y * Wl[(ch + 1) * 3 + 0];
            p1 += f.x * Wl[ch * 3 + 1] + f.y * Wl[(ch + 1) * 3 + 1];
            p2 += f.x * Wl[ch * 3 + 2] + f.y * Wl[(ch + 1) * 3 + 2];
        }
    }
    out[node * 3 + 0] = p0;
    out[node * 3 + 1] = p1;
    out[node * 3 + 2] = p2;
}

extern "C" void kernel_launch(void* const* d_in, const int* in_sizes, int n_in,
                              void* d_out, int out_size, void* d_ws, size_t ws_size,
                              hipStream_t stream) {
    const float* x  = (const float*)d_in[0];
    const int*   ei = (const int*)d_in[1];
    const float* Ws = (const float*)d_in[2];
    const float* bs = (const float*)d_in[3];
    const float* Wc = (const float*)d_in[4];
    const float* bc = (const float*)d_in[5];
    float* out = (float*)d_out;

    int E = in_sizes[1] / 2;
    const int* src = ei;
    const int* dst = ei + E;
    int nchunks = (E + P1_CHUNK - 1) / P1_CHUNK;

    char* wsb = (char*)d_ws;
    size_t off = 0;
    int*      bcnt    = (int*)(wsb + off); off += 512 * 4;
    int*      boff    = (int*)(wsb + off); off += 512 * 4;
    int*      bcur    = (int*)(wsb + off); off += 512 * 4;
    int*      row_ptr = (int*)(wsb + off); off += 100608 * 4;
    float*    dinv    = (float*)(wsb + off); off += 100352 * 4;
    int*      csr_src = (int*)(wsb + off); off += ((size_t)E + 256) * 4;
    unsigned* ebuf    = (unsigned*)(wsb + off); off += (size_t)E * 4;
    float4*   h       = (float4*)(wsb + off); off += (size_t)8 * PSTR * 16;  // sliced fp16
    float4*   xa      = (float4*)(wsb + off); off += (size_t)8 * PSTR * 16;
    float4*   xb      = (float4*)(wsb + off); off += (size_t)8 * PSTR * 16;

    // graph build
    hipMemsetAsync(bcnt, 0, 512 * sizeof(int), stream);
    hist_kernel<<<nchunks, 256, 0, stream>>>(dst, bcnt, E);
    bscan_kernel<<<1, 512, 0, stream>>>(bcnt, boff, bcur, row_ptr, E, NN);
    p1_kernel<<<nchunks, 256, 0, stream>>>(src, dst, bcur, ebuf, E);
    p2_kernel<<<NB, 256, 0, stream>>>(ebuf, boff, row_ptr, dinv, csr_src, NN);

    // layers (ping-pong sliced fp16 xa/xb)
    const void* xin = (const void*)x;
    int xin_half = 0;
    float4* bufs[2] = {xa, xb};
    int nblk = (NN + 255) / 256;
    for (int l = 0; l < 4; ++l) {
        float4* xout = bufs[l & 1];
        matmul64_kernel<<<(NN + 63) / 64, 256, 0, stream>>>(
            xin, xin_half, Ws + (size_t)l * HD * HD, dinv, h, NN);
        agg_kernel<<<nblk * 8, 256, 0, stream>>>(
            h, row_ptr, csr_src, dinv, bs + l * HD, (const float4*)xin, xout, NN, l > 0);
        xin = (const void*)xout;
        xin_half = 1;
    }
    proj_kernel<<<(NN + 255) / 256, 256, 0, stream>>>(bufs[1], Wc, bc, out, NN);
}

// Round 15
// 442.890 us; speedup vs baseline: 5.3496x; 1.1111x over previous
//
#include <hip/hip_runtime.h>
#include <hip/hip_fp16.h>

#define NN 100000
#define HD 64
#define NB ((NN + 255) >> 8)   // 391 dst-buckets of 256 nodes
#define P1_CHUNK 8192
#define PSTR4 100352            // plane stride in rows (each row 32B = 8 dwords)

// k1: per-chunk LDS histogram of dst>>8 -> global bucket counts
__global__ __launch_bounds__(256) void hist_kernel(const int* __restrict__ dst,
                                                   int* __restrict__ bcnt, int E) {
    __shared__ int hist[NB];
    int t = threadIdx.x;
    int e0 = blockIdx.x * P1_CHUNK;
    int count = min(P1_CHUNK, E - e0);
    for (int b = t; b < NB; b += 256) hist[b] = 0;
    __syncthreads();
    for (int i = t; i < count; i += 256) atomicAdd(&hist[dst[e0 + i] >> 8], 1);
    __syncthreads();
    for (int b = t; b < NB; b += 256) {
        int c = hist[b];
        if (c) atomicAdd(&bcnt[b], c);
    }
}

// k2: single block scan of NB bucket counts -> boff (exclusive), bcur copy
__global__ void bscan_kernel(const int* __restrict__ bcnt, int* __restrict__ boff,
                             int* __restrict__ bcur, int* __restrict__ row_ptr,
                             int E, int n) {
    __shared__ int sm[512];
    int t = threadIdx.x;
    int v = (t < NB) ? bcnt[t] : 0;
    sm[t] = v;
    __syncthreads();
    for (int off = 1; off < 512; off <<= 1) {
        int u = (t >= off) ? sm[t - off] : 0;
        __syncthreads();
        sm[t] += u;
        __syncthreads();
    }
    if (t < NB) {
        boff[t] = sm[t] - v;
        bcur[t] = sm[t] - v;
    }
    if (t == 0) {
        boff[NB] = E;
        row_ptr[n] = E;
    }
}

// k3: chunked bucket scatter — ebuf entry packed: (d & 255) << 24 | src
__global__ __launch_bounds__(256) void p1_kernel(const int* __restrict__ src,
                                                 const int* __restrict__ dst,
                                                 int* __restrict__ bcur,
                                                 unsigned* __restrict__ ebuf, int E) {
    __shared__ int hist[NB];
    __shared__ int cur[NB];
    int t = threadIdx.x;
    int e0 = blockIdx.x * P1_CHUNK;
    int count = min(P1_CHUNK, E - e0);
    for (int b = t; b < NB; b += 256) hist[b] = 0;
    __syncthreads();
    for (int i = t; i < count; i += 256) atomicAdd(&hist[dst[e0 + i] >> 8], 1);
    __syncthreads();
    for (int b = t; b < NB; b += 256) {
        int c = hist[b];
        cur[b] = c ? atomicAdd(&bcur[b], c) : 0;
    }
    __syncthreads();
    for (int i = t; i < count; i += 256) {
        int d = dst[e0 + i], s = src[e0 + i];
        int pos = atomicAdd(&cur[d >> 8], 1);
        ebuf[pos] = ((unsigned)(d & 255) << 24) | (unsigned)s;
    }
}

// k4: one block per bucket — LDS degree count + scan -> row_ptr/dinv, then local CSR scatter
__global__ __launch_bounds__(256) void p2_kernel(const unsigned* __restrict__ ebuf,
                                                 const int* __restrict__ boff,
                                                 int* __restrict__ row_ptr,
                                                 float* __restrict__ dinv,
                                                 int* __restrict__ csr_src, int n) {
    __shared__ int cnt[256];
    __shared__ int cur[256];
    int b = blockIdx.x;
    int node0 = b << 8;
    int t = threadIdx.x;
    int beg = boff[b], end = boff[b + 1];
    cnt[t] = 0;
    __syncthreads();
    for (int i = beg + t; i < end; i += 256) atomicAdd(&cnt[ebuf[i] >> 24], 1);
    __syncthreads();
    int deg = cnt[t];
    for (int off = 1; off < 256; off <<= 1) {   // inclusive scan
        int v = (t >= off) ? cnt[t - off] : 0;
        __syncthreads();
        cnt[t] += v;
        __syncthreads();
    }
    int excl = cnt[t] - deg;
    int node = node0 + t;
    if (node < n) {
        row_ptr[node] = beg + excl;
        dinv[node] = rsqrtf((float)deg + 1.0f);   // +1 = self loop
    }
    cur[t] = beg + excl;
    __syncthreads();
    for (int i = beg + t; i < end; i += 256) {
        unsigned p = ebuf[i];
        int pos = atomicAdd(&cur[p >> 24], 1);
        csr_src[pos] = (int)(p & 0xFFFFFFu);
    }
}

// H(fp16, 4 slice-planes of 16ch) = (X @ W) * dinv[row] — 64x64 tile, 4x4 micro-tile.
__global__ __launch_bounds__(256) void matmul64_kernel(const void* __restrict__ Xv,
                                                       int x_is_half,
                                                       const float* __restrict__ W,
                                                       const float* __restrict__ dinv,
                                                       float2* __restrict__ H2, int n) {
    __shared__ float Wl[64 * 64];      // [k][c]
    __shared__ float Xs[64 * 65];      // [r][k], padded
    int tid = threadIdx.x;
    int row0 = blockIdx.x * 64;
    const float4* W4 = (const float4*)W;
    float4* Wl4 = (float4*)Wl;
#pragma unroll
    for (int i = 0; i < 4; ++i) Wl4[tid + 256 * i] = W4[tid + 256 * i];
    if (x_is_half) {
        const float4* X4 = (const float4*)Xv;   // 4 planes; row = 2 float4 per plane
#pragma unroll
        for (int i = 0; i < 2; ++i) {
            int l = tid + 256 * i;              // 512 = 64 rows x 4 planes x 2 halves
            int r = l >> 3, rem = l & 7;
            int p = rem >> 1, hh = rem & 1;
            int row = row0 + r;
            float4 xv = (row < n) ? X4[((size_t)p * PSTR4 + row) * 2 + hh]
                                  : make_float4(0.f, 0.f, 0.f, 0.f);
            const __half2* hp = (const __half2*)&xv;
#pragma unroll
            for (int j = 0; j < 4; ++j) {
                float2 f = __half22float2(hp[j]);
                Xs[r * 65 + p * 16 + hh * 8 + 2 * j]     = f.x;
                Xs[r * 65 + p * 16 + hh * 8 + 2 * j + 1] = f.y;
            }
        }
    } else {
        const float4* X4 = (const float4*)Xv;
#pragma unroll
        for (int i = 0; i < 4; ++i) {
            int l = tid + 256 * i;              // 1024 = 64 rows x 16
            int r = l >> 4, k0 = (l & 15) * 4;
            int row = row0 + r;
            float4 xv = (row < n) ? X4[(size_t)row * 16 + (l & 15)]
                                  : make_float4(0.f, 0.f, 0.f, 0.f);
            Xs[r * 65 + k0 + 0] = xv.x;
            Xs[r * 65 + k0 + 1] = xv.y;
            Xs[r * 65 + k0 + 2] = xv.z;
            Xs[r * 65 + k0 + 3] = xv.w;
        }
    }
    __syncthreads();
    int tx = tid & 15, ty = tid >> 4;   // cols c0=4*tx, rows r0=4*ty
    float acc[4][4] = {};
    const float4* Wlr4 = (const float4*)Wl;
#pragma unroll 4
    for (int k = 0; k < 64; ++k) {
        float4 b = Wlr4[k * 16 + tx];
        float a0 = Xs[(ty * 4 + 0) * 65 + k];
        float a1 = Xs[(ty * 4 + 1) * 65 + k];
        float a2 = Xs[(ty * 4 + 2) * 65 + k];
        float a3 = Xs[(ty * 4 + 3) * 65 + k];
        acc[0][0] += a0 * b.x; acc[0][1] += a0 * b.y; acc[0][2] += a0 * b.z; acc[0][3] += a0 * b.w;
        acc[1][0] += a1 * b.x; acc[1][1] += a1 * b.y; acc[1][2] += a1 * b.z; acc[1][3] += a1 * b.w;
        acc[2][0] += a2 * b.x; acc[2][1] += a2 * b.y; acc[2][2] += a2 * b.z; acc[2][3] += a2 * b.w;
        acc[3][0] += a3 * b.x; acc[3][1] += a3 * b.y; acc[3][2] += a3 * b.z; acc[3][3] += a3 * b.w;
    }
    int p = tx >> 2, quad = tx & 3;     // plane, float2-slot within 32B row
#pragma unroll
    for (int j = 0; j < 4; ++j) {
        int row = row0 + ty * 4 + j;
        if (row < n) {
            float dn = dinv[row];
            __half2 p01 = __float22half2_rn(make_float2(acc[j][0] * dn, acc[j][1] * dn));
            __half2 p23 = __float22half2_rn(make_float2(acc[j][2] * dn, acc[j][3] * dn));
            float2 st;
            st.x = *reinterpret_cast<float*>(&p01);
            st.y = *reinterpret_cast<float*>(&p23);
            H2[((size_t)p * PSTR4 + row) * 4 + quad] = st;
        }
    }
}

#define H2_ADD(V) do {                                                       \
    __half2 _h = *reinterpret_cast<const __half2*>(&(V));                    \
    float2 _f = __half22float2(_h);                                          \
    ax += _f.x; ay += _f.y;                                                  \
} while (0)

// agg: octet (8 lanes) per node, slice = blockIdx & 3 (XCD-L2 affinity, plane 3.2MB).
// lane sub owns 2 channels; per edge: shfl broadcast + 4B load (32B coalesced/octet).
__global__ __launch_bounds__(256) void agg_kernel(const unsigned* __restrict__ hdw,
                                                  const int* __restrict__ row_ptr,
                                                  const int* __restrict__ csr_src,
                                                  const float* __restrict__ dinv,
                                                  const float* __restrict__ b,
                                                  const unsigned* __restrict__ xprev,
                                                  unsigned* __restrict__ xout,
                                                  int n, int residual) {
    int s = blockIdx.x & 3;
    int node = (blockIdx.x >> 2) * 32 + (threadIdx.x >> 3);
    int sub = threadIdx.x & 7;
    bool active = node < n;
    int nc = active ? node : 0;
    int beg = row_ptr[nc], end = row_ptr[nc + 1];
    const unsigned* hp = hdw + (size_t)s * PSTR4 * 8;
    float ax = 0.f, ay = 0.f;
    int base = (threadIdx.x & 63) & ~7;   // octet base lane in wave
    for (int k = beg; k < end; k += 8) {
        int p = k + sub;
        int sv = (p < end) ? csr_src[p] : 0;
        int m = end - k;
        if (m >= 8) {
            int s0 = __shfl(sv, base + 0);
            int s1 = __shfl(sv, base + 1);
            int s2 = __shfl(sv, base + 2);
            int s3 = __shfl(sv, base + 3);
            int s4 = __shfl(sv, base + 4);
            int s5 = __shfl(sv, base + 5);
            int s6 = __shfl(sv, base + 6);
            int s7 = __shfl(sv, base + 7);
            unsigned v0 = hp[(size_t)s0 * 8 + sub];
            unsigned v1 = hp[(size_t)s1 * 8 + sub];
            unsigned v2 = hp[(size_t)s2 * 8 + sub];
            unsigned v3 = hp[(size_t)s3 * 8 + sub];
            unsigned v4 = hp[(size_t)s4 * 8 + sub];
            unsigned v5 = hp[(size_t)s5 * 8 + sub];
            unsigned v6 = hp[(size_t)s6 * 8 + sub];
            unsigned v7 = hp[(size_t)s7 * 8 + sub];
            H2_ADD(v0); H2_ADD(v1); H2_ADD(v2); H2_ADD(v3);
            H2_ADD(v4); H2_ADD(v5); H2_ADD(v6); H2_ADD(v7);
        } else {
            for (int i = 0; i < m; ++i) {
                int si = __shfl(sv, base + i);
                unsigned v = hp[(size_t)si * 8 + sub];
                H2_ADD(v);
            }
        }
    }
    {
        unsigned v = hp[(size_t)nc * 8 + sub];   // self loop (pre-scaled by dinv[src])
        H2_ADD(v);
    }
    if (active) {
        float dn = dinv[node];
        float vx = ax * dn + b[s * 16 + sub * 2];
        float vy = ay * dn + b[s * 16 + sub * 2 + 1];
        if (residual) {
            unsigned r = xprev[((size_t)s * PSTR4 + node) * 8 + sub];
            __half2 rh = *reinterpret_cast<__half2*>(&r);
            float2 rf = __half22float2(rh);
            vx += rf.x; vy += rf.y;
        }
        vx = fmaxf(vx, 0.f);
        vy = fmaxf(vy, 0.f);
        __half2 oh = __float22half2_rn(make_float2(vx, vy));
        xout[((size_t)s * PSTR4 + node) * 8 + sub] = *reinterpret_cast<unsigned*>(&oh);
    }
}

// final 64->3 projection from 4-plane fp16 activations
__global__ __launch_bounds__(256) void proj_kernel(const float4* __restrict__ xc4,
                                                   const float* __restrict__ Wc,
                                                   const float* __restrict__ bc,
                                                   float* __restrict__ out, int n) {
    __shared__ float Wl[192];
    int t = threadIdx.x;
    if (t < 192) Wl[t] = Wc[t];
    __syncthreads();
    int node = blockIdx.x * 256 + t;
    if (node >= n) return;
    float p0 = bc[0], p1 = bc[1], p2 = bc[2];
#pragma unroll
    for (int p = 0; p < 4; ++p) {
#pragma unroll
        for (int hh = 0; hh < 2; ++hh) {
            float4 v = xc4[((size_t)p * PSTR4 + node) * 2 + hh];
            const __half2* q = (const __half2*)&v;
#pragma unroll
            for (int j = 0; j < 4; ++j) {
                float2 f = __half22float2(q[j]);
                int ch = p * 16 + hh * 8 + j * 2;
                p0 += f.x * Wl[ch * 3 + 0] + f.y * Wl[(ch + 1) * 3 + 0];
                p1 += f.x * Wl[ch * 3 + 1] + f.y * Wl[(ch + 1) * 3 + 1];
                p2 += f.x * Wl[ch * 3 + 2] + f.y * Wl[(ch + 1) * 3 + 2];
            }
        }
    }
    out[node * 3 + 0] = p0;
    out[node * 3 + 1] = p1;
    out[node * 3 + 2] = p2;
}

extern "C" void kernel_launch(void* const* d_in, const int* in_sizes, int n_in,
                              void* d_out, int out_size, void* d_ws, size_t ws_size,
                              hipStream_t stream) {
    const float* x  = (const float*)d_in[0];
    const int*   ei = (const int*)d_in[1];
    const float* Ws = (const float*)d_in[2];
    const float* bs = (const float*)d_in[3];
    const float* Wc = (const float*)d_in[4];
    const float* bc = (const float*)d_in[5];
    float* out = (float*)d_out;

    int E = in_sizes[1] / 2;
    const int* src = ei;
    const int* dst = ei + E;
    int nchunks = (E + P1_CHUNK - 1) / P1_CHUNK;

    char* wsb = (char*)d_ws;
    size_t off = 0;
    int*      bcnt    = (int*)(wsb + off); off += 512 * 4;
    int*      boff    = (int*)(wsb + off); off += 512 * 4;
    int*      bcur    = (int*)(wsb + off); off += 512 * 4;
    int*      row_ptr = (int*)(wsb + off); off += 100608 * 4;
    float*    dinv    = (float*)(wsb + off); off += 100352 * 4;
    int*      csr_src = (int*)(wsb + off); off += ((size_t)E + 256) * 4;
    unsigned* ebuf    = (unsigned*)(wsb + off); off += (size_t)E * 4;
    char*     h       = wsb + off; off += (size_t)4 * PSTR4 * 32;  // 4 fp16 planes
    char*     xa      = wsb + off; off += (size_t)4 * PSTR4 * 32;
    char*     xb      = wsb + off; off += (size_t)4 * PSTR4 * 32;

    // graph build
    hipMemsetAsync(bcnt, 0, 512 * sizeof(int), stream);
    hist_kernel<<<nchunks, 256, 0, stream>>>(dst, bcnt, E);
    bscan_kernel<<<1, 512, 0, stream>>>(bcnt, boff, bcur, row_ptr, E, NN);
    p1_kernel<<<nchunks, 256, 0, stream>>>(src, dst, bcur, ebuf, E);
    p2_kernel<<<NB, 256, 0, stream>>>(ebuf, boff, row_ptr, dinv, csr_src, NN);

    // layers (ping-pong 4-plane fp16 xa/xb)
    const void* xin = (const void*)x;
    int xin_half = 0;
    char* bufs[2] = {xa, xb};
    int agg_grid = ((NN + 31) / 32) * 4;   // node-blocks x 4 slices
    for (int l = 0; l < 4; ++l) {
        char* xout = bufs[l & 1];
        matmul64_kernel<<<(NN + 63) / 64, 256, 0, stream>>>(
            xin, xin_half, Ws + (size_t)l * HD * HD, dinv, (float2*)h, NN);
        agg_kernel<<<agg_grid, 256, 0, stream>>>(
            (const unsigned*)h, row_ptr, csr_src, dinv, bs + l * HD,
            (const unsigned*)xin, (unsigned*)xout, NN, l > 0);
        xin = (const void*)xout;
        xin_half = 1;
    }
    proj_kernel<<<(NN + 255) / 256, 256, 0, stream>>>((const float4*)bufs[1], Wc, bc, out, NN);
}

// Round 16
// 387.424 us; speedup vs baseline: 6.1154x; 1.1432x over previous
//
#include <hip/hip_runtime.h>
#include <hip/hip_fp16.h>

#define NN 100000
#define HD 64
#define NB ((NN + 255) >> 8)   // 391 dst-buckets of 256 nodes
#define P1_CHUNK 8192
#define PSTR4 100352            // plane stride in rows (each row 32B)

// k1: per-chunk LDS histogram of dst>>8 -> global bucket counts
__global__ __launch_bounds__(256) void hist_kernel(const int* __restrict__ dst,
                                                   int* __restrict__ bcnt, int E) {
    __shared__ int hist[NB];
    int t = threadIdx.x;
    int e0 = blockIdx.x * P1_CHUNK;
    int count = min(P1_CHUNK, E - e0);
    for (int b = t; b < NB; b += 256) hist[b] = 0;
    __syncthreads();
    for (int i = t; i < count; i += 256) atomicAdd(&hist[dst[e0 + i] >> 8], 1);
    __syncthreads();
    for (int b = t; b < NB; b += 256) {
        int c = hist[b];
        if (c) atomicAdd(&bcnt[b], c);
    }
}

// k2: single block scan of NB bucket counts -> boff (exclusive), bcur copy
__global__ void bscan_kernel(const int* __restrict__ bcnt, int* __restrict__ boff,
                             int* __restrict__ bcur, int* __restrict__ row_ptr,
                             int E, int n) {
    __shared__ int sm[512];
    int t = threadIdx.x;
    int v = (t < NB) ? bcnt[t] : 0;
    sm[t] = v;
    __syncthreads();
    for (int off = 1; off < 512; off <<= 1) {
        int u = (t >= off) ? sm[t - off] : 0;
        __syncthreads();
        sm[t] += u;
        __syncthreads();
    }
    if (t < NB) {
        boff[t] = sm[t] - v;
        bcur[t] = sm[t] - v;
    }
    if (t == 0) {
        boff[NB] = E;
        row_ptr[n] = E;
    }
}

// k3: chunked bucket scatter — ebuf entry packed: (d & 255) << 24 | src
__global__ __launch_bounds__(256) void p1_kernel(const int* __restrict__ src,
                                                 const int* __restrict__ dst,
                                                 int* __restrict__ bcur,
                                                 unsigned* __restrict__ ebuf, int E) {
    __shared__ int hist[NB];
    __shared__ int cur[NB];
    int t = threadIdx.x;
    int e0 = blockIdx.x * P1_CHUNK;
    int count = min(P1_CHUNK, E - e0);
    for (int b = t; b < NB; b += 256) hist[b] = 0;
    __syncthreads();
    for (int i = t; i < count; i += 256) atomicAdd(&hist[dst[e0 + i] >> 8], 1);
    __syncthreads();
    for (int b = t; b < NB; b += 256) {
        int c = hist[b];
        cur[b] = c ? atomicAdd(&bcur[b], c) : 0;
    }
    __syncthreads();
    for (int i = t; i < count; i += 256) {
        int d = dst[e0 + i], s = src[e0 + i];
        int pos = atomicAdd(&cur[d >> 8], 1);
        ebuf[pos] = ((unsigned)(d & 255) << 24) | (unsigned)s;
    }
}

// k4: one block per bucket — LDS degree count + scan -> row_ptr/dinv, then local CSR scatter
__global__ __launch_bounds__(256) void p2_kernel(const unsigned* __restrict__ ebuf,
                                                 const int* __restrict__ boff,
                                                 int* __restrict__ row_ptr,
                                                 float* __restrict__ dinv,
                                                 int* __restrict__ csr_src, int n) {
    __shared__ int cnt[256];
    __shared__ int cur[256];
    int b = blockIdx.x;
    int node0 = b << 8;
    int t = threadIdx.x;
    int beg = boff[b], end = boff[b + 1];
    cnt[t] = 0;
    __syncthreads();
    for (int i = beg + t; i < end; i += 256) atomicAdd(&cnt[ebuf[i] >> 24], 1);
    __syncthreads();
    int deg = cnt[t];
    for (int off = 1; off < 256; off <<= 1) {   // inclusive scan
        int v = (t >= off) ? cnt[t - off] : 0;
        __syncthreads();
        cnt[t] += v;
        __syncthreads();
    }
    int excl = cnt[t] - deg;
    int node = node0 + t;
    if (node < n) {
        row_ptr[node] = beg + excl;
        dinv[node] = rsqrtf((float)deg + 1.0f);   // +1 = self loop
    }
    cur[t] = beg + excl;
    __syncthreads();
    for (int i = beg + t; i < end; i += 256) {
        unsigned p = ebuf[i];
        int pos = atomicAdd(&cur[p >> 24], 1);
        csr_src[pos] = (int)(p & 0xFFFFFFu);
    }
}

// H(fp16, 4 slice-planes of 16ch) = (X @ W) * dinv[row] — 64x64 tile, 4x4 micro-tile.
__global__ __launch_bounds__(256) void matmul64_kernel(const void* __restrict__ Xv,
                                                       int x_is_half,
                                                       const float* __restrict__ W,
                                                       const float* __restrict__ dinv,
                                                       float2* __restrict__ H2, int n) {
    __shared__ float Wl[64 * 64];      // [k][c]
    __shared__ float Xs[64 * 65];      // [r][k], padded
    int tid = threadIdx.x;
    int row0 = blockIdx.x * 64;
    const float4* W4 = (const float4*)W;
    float4* Wl4 = (float4*)Wl;
#pragma unroll
    for (int i = 0; i < 4; ++i) Wl4[tid + 256 * i] = W4[tid + 256 * i];
    if (x_is_half) {
        const float4* X4 = (const float4*)Xv;   // 4 planes; row = 2 float4 per plane
#pragma unroll
        for (int i = 0; i < 2; ++i) {
            int l = tid + 256 * i;              // 512 = 64 rows x 4 planes x 2 halves
            int r = l >> 3, rem = l & 7;
            int p = rem >> 1, hh = rem & 1;
            int row = row0 + r;
            float4 xv = (row < n) ? X4[((size_t)p * PSTR4 + row) * 2 + hh]
                                  : make_float4(0.f, 0.f, 0.f, 0.f);
            const __half2* hp = (const __half2*)&xv;
#pragma unroll
            for (int j = 0; j < 4; ++j) {
                float2 f = __half22float2(hp[j]);
                Xs[r * 65 + p * 16 + hh * 8 + 2 * j]     = f.x;
                Xs[r * 65 + p * 16 + hh * 8 + 2 * j + 1] = f.y;
            }
        }
    } else {
        const float4* X4 = (const float4*)Xv;
#pragma unroll
        for (int i = 0; i < 4; ++i) {
            int l = tid + 256 * i;              // 1024 = 64 rows x 16
            int r = l >> 4, k0 = (l & 15) * 4;
            int row = row0 + r;
            float4 xv = (row < n) ? X4[(size_t)row * 16 + (l & 15)]
                                  : make_float4(0.f, 0.f, 0.f, 0.f);
            Xs[r * 65 + k0 + 0] = xv.x;
            Xs[r * 65 + k0 + 1] = xv.y;
            Xs[r * 65 + k0 + 2] = xv.z;
            Xs[r * 65 + k0 + 3] = xv.w;
        }
    }
    __syncthreads();
    int tx = tid & 15, ty = tid >> 4;   // cols c0=4*tx, rows r0=4*ty
    float acc[4][4] = {};
    const float4* Wlr4 = (const float4*)Wl;
#pragma unroll 4
    for (int k = 0; k < 64; ++k) {
        float4 b = Wlr4[k * 16 + tx];
        float a0 = Xs[(ty * 4 + 0) * 65 + k];
        float a1 = Xs[(ty * 4 + 1) * 65 + k];
        float a2 = Xs[(ty * 4 + 2) * 65 + k];
        float a3 = Xs[(ty * 4 + 3) * 65 + k];
        acc[0][0] += a0 * b.x; acc[0][1] += a0 * b.y; acc[0][2] += a0 * b.z; acc[0][3] += a0 * b.w;
        acc[1][0] += a1 * b.x; acc[1][1] += a1 * b.y; acc[1][2] += a1 * b.z; acc[1][3] += a1 * b.w;
        acc[2][0] += a2 * b.x; acc[2][1] += a2 * b.y; acc[2][2] += a2 * b.z; acc[2][3] += a2 * b.w;
        acc[3][0] += a3 * b.x; acc[3][1] += a3 * b.y; acc[3][2] += a3 * b.z; acc[3][3] += a3 * b.w;
    }
    int p = tx >> 2, quad = tx & 3;     // plane, float2-slot within 32B row
#pragma unroll
    for (int j = 0; j < 4; ++j) {
        int row = row0 + ty * 4 + j;
        if (row < n) {
            float dn = dinv[row];
            __half2 p01 = __float22half2_rn(make_float2(acc[j][0] * dn, acc[j][1] * dn));
            __half2 p23 = __float22half2_rn(make_float2(acc[j][2] * dn, acc[j][3] * dn));
            float2 st;
            st.x = *reinterpret_cast<float*>(&p01);
            st.y = *reinterpret_cast<float*>(&p23);
            H2[((size_t)p * PSTR4 + row) * 4 + quad] = st;
        }
    }
}

#define UNP8(V) do {                                                         \
    const __half2* _q = (const __half2*)&(V);                                \
    float2 _f0 = __half22float2(_q[0]);                                      \
    float2 _f1 = __half22float2(_q[1]);                                      \
    float2 _f2 = __half22float2(_q[2]);                                      \
    float2 _f3 = __half22float2(_q[3]);                                      \
    a[0] += _f0.x; a[1] += _f0.y; a[2] += _f1.x; a[3] += _f1.y;              \
    a[4] += _f2.x; a[5] += _f2.y; a[6] += _f3.x; a[7] += _f3.y;              \
} while (0)

// agg: octet per node, slice = blockIdx & 3 (L2-resident 3.2MB plane).
// lane sub = (edge-slot e in [0,4), half hh in [0,2)): per load instruction an
// octet gathers 4 edges x 32B = 128B. fp32 acc; shfl_xor reduce over e; sub<2 epilogue.
__global__ __launch_bounds__(256) void agg_kernel(const float4* __restrict__ hb,
                                                  const int* __restrict__ row_ptr,
                                                  const int* __restrict__ csr_src,
                                                  const float* __restrict__ dinv,
                                                  const float* __restrict__ b,
                                                  const float4* __restrict__ xprev,
                                                  float4* __restrict__ xout,
                                                  int n, int residual) {
    int s = blockIdx.x & 3;
    int lane = threadIdx.x & 63;
    int oct = lane >> 3, sub = lane & 7;
    int e = sub >> 1, hh = sub & 1;
    int node = (blockIdx.x >> 2) * 32 + (threadIdx.x >> 6) * 8 + oct;
    bool active = node < n;
    int nc = active ? node : 0;
    int beg = row_ptr[nc], end = row_ptr[nc + 1];
    const float4* hp = hb + (size_t)s * PSTR4 * 2;   // rows of 2 float4
    float a[8] = {0.f, 0.f, 0.f, 0.f, 0.f, 0.f, 0.f, 0.f};
    int base = lane & ~7;
    // double-buffered csr batch: prefetch next 8 indices while gathering current
    int p0 = beg + sub;
    int sv = (p0 < end) ? csr_src[p0] : 0;
    for (int k = beg; k < end; k += 8) {
        int np = k + 8 + sub;
        int svn = (np < end) ? csr_src[np] : 0;
        int m = end - k;
        int si0 = __shfl(sv, base + e);
        int si1 = __shfl(sv, base + 4 + e);
        if (e < m) {
            float4 v = hp[(size_t)si0 * 2 + hh];
            UNP8(v);
        }
        if (4 + e < m) {
            float4 v = hp[(size_t)si1 * 2 + hh];
            UNP8(v);
        }
        sv = svn;
    }
    // reduce over edge-slot e (sub bits 1-2)
#pragma unroll
    for (int c = 0; c < 8; ++c) {
        a[c] += __shfl_xor(a[c], 2);
        a[c] += __shfl_xor(a[c], 4);
    }
    if (active && sub < 2) {
        {
            float4 v = hp[(size_t)nc * 2 + hh];   // self loop (pre-scaled by dinv[src])
            UNP8(v);
        }
        float dn = dinv[node];
        int cb = s * 16 + hh * 8;
        float vch[8];
#pragma unroll
        for (int c = 0; c < 8; ++c) vch[c] = a[c] * dn + b[cb + c];
        if (residual) {
            float4 rr = xprev[((size_t)s * PSTR4 + node) * 2 + hh];
            const __half2* rp = (const __half2*)&rr;
            float2 r0 = __half22float2(rp[0]);
            float2 r1 = __half22float2(rp[1]);
            float2 r2 = __half22float2(rp[2]);
            float2 r3 = __half22float2(rp[3]);
            vch[0] += r0.x; vch[1] += r0.y; vch[2] += r1.x; vch[3] += r1.y;
            vch[4] += r2.x; vch[5] += r2.y; vch[6] += r3.x; vch[7] += r3.y;
        }
#pragma unroll
        for (int c = 0; c < 8; ++c) vch[c] = fmaxf(vch[c], 0.f);
        __half2 o0 = __float22half2_rn(make_float2(vch[0], vch[1]));
        __half2 o1 = __float22half2_rn(make_float2(vch[2], vch[3]));
        __half2 o2 = __float22half2_rn(make_float2(vch[4], vch[5]));
        __half2 o3 = __float22half2_rn(make_float2(vch[6], vch[7]));
        float4 st;
        st.x = *reinterpret_cast<float*>(&o0);
        st.y = *reinterpret_cast<float*>(&o1);
        st.z = *reinterpret_cast<float*>(&o2);
        st.w = *reinterpret_cast<float*>(&o3);
        xout[((size_t)s * PSTR4 + node) * 2 + hh] = st;
    }
}

// final 64->3 projection from 4-plane fp16 activations
__global__ __launch_bounds__(256) void proj_kernel(const float4* __restrict__ xc4,
                                                   const float* __restrict__ Wc,
                                                   const float* __restrict__ bc,
                                                   float* __restrict__ out, int n) {
    __shared__ float Wl[192];
    int t = threadIdx.x;
    if (t < 192) Wl[t] = Wc[t];
    __syncthreads();
    int node = blockIdx.x * 256 + t;
    if (node >= n) return;
    float p0 = bc[0], p1 = bc[1], p2 = bc[2];
#pragma unroll
    for (int p = 0; p < 4; ++p) {
#pragma unroll
        for (int hh = 0; hh < 2; ++hh) {
            float4 v = xc4[((size_t)p * PSTR4 + node) * 2 + hh];
            const __half2* q = (const __half2*)&v;
#pragma unroll
            for (int j = 0; j < 4; ++j) {
                float2 f = __half22float2(q[j]);
                int ch = p * 16 + hh * 8 + j * 2;
                p0 += f.x * Wl[ch * 3 + 0] + f.y * Wl[(ch + 1) * 3 + 0];
                p1 += f.x * Wl[ch * 3 + 1] + f.y * Wl[(ch + 1) * 3 + 1];
                p2 += f.x * Wl[ch * 3 + 2] + f.y * Wl[(ch + 1) * 3 + 2];
            }
        }
    }
    out[node * 3 + 0] = p0;
    out[node * 3 + 1] = p1;
    out[node * 3 + 2] = p2;
}

extern "C" void kernel_launch(void* const* d_in, const int* in_sizes, int n_in,
                              void* d_out, int out_size, void* d_ws, size_t ws_size,
                              hipStream_t stream) {
    const float* x  = (const float*)d_in[0];
    const int*   ei = (const int*)d_in[1];
    const float* Ws = (const float*)d_in[2];
    const float* bs = (const float*)d_in[3];
    const float* Wc = (const float*)d_in[4];
    const float* bc = (const float*)d_in[5];
    float* out = (float*)d_out;

    int E = in_sizes[1] / 2;
    const int* src = ei;
    const int* dst = ei + E;
    int nchunks = (E + P1_CHUNK - 1) / P1_CHUNK;

    char* wsb = (char*)d_ws;
    size_t off = 0;
    int*      bcnt    = (int*)(wsb + off); off += 512 * 4;
    int*      boff    = (int*)(wsb + off); off += 512 * 4;
    int*      bcur    = (int*)(wsb + off); off += 512 * 4;
    int*      row_ptr = (int*)(wsb + off); off += 100608 * 4;
    float*    dinv    = (float*)(wsb + off); off += 100352 * 4;
    int*      csr_src = (int*)(wsb + off); off += ((size_t)E + 256) * 4;
    unsigned* ebuf    = (unsigned*)(wsb + off); off += (size_t)E * 4;
    char*     h       = wsb + off; off += (size_t)4 * PSTR4 * 32;  // 4 fp16 planes
    char*     xa      = wsb + off; off += (size_t)4 * PSTR4 * 32;
    char*     xb      = wsb + off; off += (size_t)4 * PSTR4 * 32;

    // graph build
    hipMemsetAsync(bcnt, 0, 512 * sizeof(int), stream);
    hist_kernel<<<nchunks, 256, 0, stream>>>(dst, bcnt, E);
    bscan_kernel<<<1, 512, 0, stream>>>(bcnt, boff, bcur, row_ptr, E, NN);
    p1_kernel<<<nchunks, 256, 0, stream>>>(src, dst, bcur, ebuf, E);
    p2_kernel<<<NB, 256, 0, stream>>>(ebuf, boff, row_ptr, dinv, csr_src, NN);

    // layers (ping-pong 4-plane fp16 xa/xb)
    const void* xin = (const void*)x;
    int xin_half = 0;
    char* bufs[2] = {xa, xb};
    int agg_grid = ((NN + 31) / 32) * 4;   // node-blocks x 4 slices
    for (int l = 0; l < 4; ++l) {
        char* xout = bufs[l & 1];
        matmul64_kernel<<<(NN + 63) / 64, 256, 0, stream>>>(
            xin, xin_half, Ws + (size_t)l * HD * HD, dinv, (float2*)h, NN);
        agg_kernel<<<agg_grid, 256, 0, stream>>>(
            (const float4*)h, row_ptr, csr_src, dinv, bs + l * HD,
            (const float4*)xin, (float4*)xout, NN, l > 0);
        xin = (const void*)xout;
        xin_half = 1;
    }
    proj_kernel<<<(NN + 255) / 256, 256, 0, stream>>>((const float4*)bufs[1], Wc, bc, out, NN);
}

// Round 17
// 362.890 us; speedup vs baseline: 6.5289x; 1.0676x over previous
//
#include <hip/hip_runtime.h>
#include <hip/hip_fp16.h>

#define NN 100000
#define HD 64
#define NB ((NN + 255) >> 8)   // 391 dst-buckets of 256 nodes
#define P1_CHUNK 8192
#define PSTR4 100352            // plane stride in rows (each row 32B)

typedef _Float16 half8 __attribute__((ext_vector_type(8)));
typedef float f32x4 __attribute__((ext_vector_type(4)));

// k1: per-chunk LDS histogram of dst>>8 -> global bucket counts
__global__ __launch_bounds__(256) void hist_kernel(const int* __restrict__ dst,
                                                   int* __restrict__ bcnt, int E) {
    __shared__ int hist[NB];
    int t = threadIdx.x;
    int e0 = blockIdx.x * P1_CHUNK;
    int count = min(P1_CHUNK, E - e0);
    for (int b = t; b < NB; b += 256) hist[b] = 0;
    __syncthreads();
    for (int i = t; i < count; i += 256) atomicAdd(&hist[dst[e0 + i] >> 8], 1);
    __syncthreads();
    for (int b = t; b < NB; b += 256) {
        int c = hist[b];
        if (c) atomicAdd(&bcnt[b], c);
    }
}

// k2: single block scan of NB bucket counts -> boff (exclusive), bcur copy
__global__ void bscan_kernel(const int* __restrict__ bcnt, int* __restrict__ boff,
                             int* __restrict__ bcur, int* __restrict__ row_ptr,
                             int E, int n) {
    __shared__ int sm[512];
    int t = threadIdx.x;
    int v = (t < NB) ? bcnt[t] : 0;
    sm[t] = v;
    __syncthreads();
    for (int off = 1; off < 512; off <<= 1) {
        int u = (t >= off) ? sm[t - off] : 0;
        __syncthreads();
        sm[t] += u;
        __syncthreads();
    }
    if (t < NB) {
        boff[t] = sm[t] - v;
        bcur[t] = sm[t] - v;
    }
    if (t == 0) {
        boff[NB] = E;
        row_ptr[n] = E;
    }
}

// k3: chunked bucket scatter — ebuf entry packed: (d & 255) << 24 | src
__global__ __launch_bounds__(256) void p1_kernel(const int* __restrict__ src,
                                                 const int* __restrict__ dst,
                                                 int* __restrict__ bcur,
                                                 unsigned* __restrict__ ebuf, int E) {
    __shared__ int hist[NB];
    __shared__ int cur[NB];
    int t = threadIdx.x;
    int e0 = blockIdx.x * P1_CHUNK;
    int count = min(P1_CHUNK, E - e0);
    for (int b = t; b < NB; b += 256) hist[b] = 0;
    __syncthreads();
    for (int i = t; i < count; i += 256) atomicAdd(&hist[dst[e0 + i] >> 8], 1);
    __syncthreads();
    for (int b = t; b < NB; b += 256) {
        int c = hist[b];
        cur[b] = c ? atomicAdd(&bcur[b], c) : 0;
    }
    __syncthreads();
    for (int i = t; i < count; i += 256) {
        int d = dst[e0 + i], s = src[e0 + i];
        int pos = atomicAdd(&cur[d >> 8], 1);
        ebuf[pos] = ((unsigned)(d & 255) << 24) | (unsigned)s;
    }
}

// k4: one block per bucket — LDS degree count + scan -> row_ptr/dinv, then local CSR scatter
__global__ __launch_bounds__(256) void p2_kernel(const unsigned* __restrict__ ebuf,
                                                 const int* __restrict__ boff,
                                                 int* __restrict__ row_ptr,
                                                 float* __restrict__ dinv,
                                                 int* __restrict__ csr_src, int n) {
    __shared__ int cnt[256];
    __shared__ int cur[256];
    int b = blockIdx.x;
    int node0 = b << 8;
    int t = threadIdx.x;
    int beg = boff[b], end = boff[b + 1];
    cnt[t] = 0;
    __syncthreads();
    for (int i = beg + t; i < end; i += 256) atomicAdd(&cnt[ebuf[i] >> 24], 1);
    __syncthreads();
    int deg = cnt[t];
    for (int off = 1; off < 256; off <<= 1) {   // inclusive scan
        int v = (t >= off) ? cnt[t - off] : 0;
        __syncthreads();
        cnt[t] += v;
        __syncthreads();
    }
    int excl = cnt[t] - deg;
    int node = node0 + t;
    if (node < n) {
        row_ptr[node] = beg + excl;
        dinv[node] = rsqrtf((float)deg + 1.0f);   // +1 = self loop
    }
    cur[t] = beg + excl;
    __syncthreads();
    for (int i = beg + t; i < end; i += 256) {
        unsigned p = ebuf[i];
        int pos = atomicAdd(&cur[p >> 24], 1);
        csr_src[pos] = (int)(p & 0xFFFFFFu);
    }
}

// MFMA matmul: H(fp16, 4 planes of 16ch) = (X @ W) * dinv[row].
// Block = 64 rows x 64 cols; wave w owns rows 16w..16w+15; 4 col-tiles x 2 K-halves.
// LDS stride 72 halves (2-way bank aliasing only). W transposed in LDS for b128 B-frags.
__global__ __launch_bounds__(256) void mfma_mm_kernel(const void* __restrict__ Xv,
                                                      int x_is_half,
                                                      const float* __restrict__ W,
                                                      const float* __restrict__ dinv,
                                                      __half* __restrict__ Hh, int n) {
    __shared__ __half Xh[64 * 72];
    __shared__ __half WT[64 * 72];   // WT[c][k] = W[k][c]
    int tid = threadIdx.x;
    int row0 = blockIdx.x * 64;
    {   // W fp32 -> fp16, transposed: thread (k = tid&63, cg = tid>>6) loads 16 cols
        int k = tid & 63, cg = tid >> 6;
        const float4* Wr = (const float4*)(W + (size_t)k * 64 + cg * 16);
        float4 w0 = Wr[0], w1 = Wr[1], w2 = Wr[2], w3 = Wr[3];
        float wv[16] = {w0.x, w0.y, w0.z, w0.w, w1.x, w1.y, w1.z, w1.w,
                        w2.x, w2.y, w2.z, w2.w, w3.x, w3.y, w3.z, w3.w};
#pragma unroll
        for (int i = 0; i < 16; ++i) WT[(cg * 16 + i) * 72 + k] = __float2half(wv[i]);
    }
    if (x_is_half) {
        const float4* X4 = (const float4*)Xv;   // 4 planes; node row = 2 float4
#pragma unroll
        for (int i = 0; i < 2; ++i) {
            int l = tid + 256 * i;              // 512 = 64 rows x 4 planes x 2 halves
            int r = l >> 3, rem = l & 7;
            int p = rem >> 1, hh = rem & 1;
            int row = row0 + r;
            float4 xv = (row < n) ? X4[((size_t)p * PSTR4 + row) * 2 + hh]
                                  : make_float4(0.f, 0.f, 0.f, 0.f);
            *(float4*)&Xh[r * 72 + p * 16 + hh * 8] = xv;   // 16B aligned
        }
    } else {
        const float4* X4 = (const float4*)Xv;
#pragma unroll
        for (int i = 0; i < 4; ++i) {
            int l = tid + 256 * i;              // 1024 = 64 rows x 16
            int r = l >> 4, k0 = (l & 15) * 4;
            int row = row0 + r;
            float4 xv = (row < n) ? X4[(size_t)row * 16 + (l & 15)]
                                  : make_float4(0.f, 0.f, 0.f, 0.f);
            __half2 h01 = __float22half2_rn(make_float2(xv.x, xv.y));
            __half2 h23 = __float22half2_rn(make_float2(xv.z, xv.w));
            float2 st;
            st.x = *reinterpret_cast<float*>(&h01);
            st.y = *reinterpret_cast<float*>(&h23);
            *(float2*)&Xh[r * 72 + k0] = st;    // 8B aligned
        }
    }
    __syncthreads();
    int w = tid >> 6, lane = tid & 63;
    int quad = lane >> 4, l16 = lane & 15;
    int mrow = w * 16 + l16;
    half8 a0 = *(const half8*)&Xh[mrow * 72 + quad * 8];
    half8 a1 = *(const half8*)&Xh[mrow * 72 + 32 + quad * 8];
    f32x4 acc[4];
#pragma unroll
    for (int c = 0; c < 4; ++c) {
        half8 b0 = *(const half8*)&WT[(c * 16 + l16) * 72 + quad * 8];
        half8 b1 = *(const half8*)&WT[(c * 16 + l16) * 72 + 32 + quad * 8];
        f32x4 z = {0.f, 0.f, 0.f, 0.f};
        z = __builtin_amdgcn_mfma_f32_16x16x32_f16(a0, b0, z, 0, 0, 0);
        z = __builtin_amdgcn_mfma_f32_16x16x32_f16(a1, b1, z, 0, 0, 0);
        acc[c] = z;
    }
    // D: col = l16, row = quad*4 + reg. Scale by dinv, store u16 into plane c.
#pragma unroll
    for (int r = 0; r < 4; ++r) {
        int node = row0 + w * 16 + quad * 4 + r;
        if (node < n) {
            float dn = dinv[node];
#pragma unroll
            for (int c = 0; c < 4; ++c) {
                Hh[((size_t)c * PSTR4 + node) * 16 + l16] = __float2half(acc[c][r] * dn);
            }
        }
    }
}

#define UNP8(V) do {                                                         \
    const __half2* _q = (const __half2*)&(V);                                \
    float2 _f0 = __half22float2(_q[0]);                                      \
    float2 _f1 = __half22float2(_q[1]);                                      \
    float2 _f2 = __half22float2(_q[2]);                                      \
    float2 _f3 = __half22float2(_q[3]);                                      \
    a[0] += _f0.x; a[1] += _f0.y; a[2] += _f1.x; a[3] += _f1.y;              \
    a[4] += _f2.x; a[5] += _f2.y; a[6] += _f3.x; a[7] += _f3.y;              \
} while (0)

// agg: octet per node, slice = blockIdx & 3 (L2-resident 3.2MB plane).
// lane sub = (edge-slot e in [0,4), half hh in [0,2)): per load instruction an
// octet gathers 4 edges x 32B = 128B. fp32 acc; shfl_xor reduce over e; sub<2 epilogue.
__global__ __launch_bounds__(256) void agg_kernel(const float4* __restrict__ hb,
                                                  const int* __restrict__ row_ptr,
                                                  const int* __restrict__ csr_src,
                                                  const float* __restrict__ dinv,
                                                  const float* __restrict__ b,
                                                  const float4* __restrict__ xprev,
                                                  float4* __restrict__ xout,
                                                  int n, int residual) {
    int s = blockIdx.x & 3;
    int lane = threadIdx.x & 63;
    int oct = lane >> 3, sub = lane & 7;
    int e = sub >> 1, hh = sub & 1;
    int node = (blockIdx.x >> 2) * 32 + (threadIdx.x >> 6) * 8 + oct;
    bool active = node < n;
    int nc = active ? node : 0;
    int beg = row_ptr[nc], end = row_ptr[nc + 1];
    const float4* hp = hb + (size_t)s * PSTR4 * 2;   // rows of 2 float4
    float a[8] = {0.f, 0.f, 0.f, 0.f, 0.f, 0.f, 0.f, 0.f};
    int base = lane & ~7;
    int p0 = beg + sub;
    int sv = (p0 < end) ? csr_src[p0] : 0;
    for (int k = beg; k < end; k += 8) {
        int np = k + 8 + sub;
        int svn = (np < end) ? csr_src[np] : 0;
        int m = end - k;
        int si0 = __shfl(sv, base + e);
        int si1 = __shfl(sv, base + 4 + e);
        if (e < m) {
            float4 v = hp[(size_t)si0 * 2 + hh];
            UNP8(v);
        }
        if (4 + e < m) {
            float4 v = hp[(size_t)si1 * 2 + hh];
            UNP8(v);
        }
        sv = svn;
    }
#pragma unroll
    for (int c = 0; c < 8; ++c) {
        a[c] += __shfl_xor(a[c], 2);
        a[c] += __shfl_xor(a[c], 4);
    }
    if (active && sub < 2) {
        {
            float4 v = hp[(size_t)nc * 2 + hh];   // self loop (pre-scaled by dinv[src])
            UNP8(v);
        }
        float dn = dinv[node];
        int cb = s * 16 + hh * 8;
        float vch[8];
#pragma unroll
        for (int c = 0; c < 8; ++c) vch[c] = a[c] * dn + b[cb + c];
        if (residual) {
            float4 rr = xprev[((size_t)s * PSTR4 + node) * 2 + hh];
            const __half2* rp = (const __half2*)&rr;
            float2 r0 = __half22float2(rp[0]);
            float2 r1 = __half22float2(rp[1]);
            float2 r2 = __half22float2(rp[2]);
            float2 r3 = __half22float2(rp[3]);
            vch[0] += r0.x; vch[1] += r0.y; vch[2] += r1.x; vch[3] += r1.y;
            vch[4] += r2.x; vch[5] += r2.y; vch[6] += r3.x; vch[7] += r3.y;
        }
#pragma unroll
        for (int c = 0; c < 8; ++c) vch[c] = fmaxf(vch[c], 0.f);
        __half2 o0 = __float22half2_rn(make_float2(vch[0], vch[1]));
        __half2 o1 = __float22half2_rn(make_float2(vch[2], vch[3]));
        __half2 o2 = __float22half2_rn(make_float2(vch[4], vch[5]));
        __half2 o3 = __float22half2_rn(make_float2(vch[6], vch[7]));
        float4 st;
        st.x = *reinterpret_cast<float*>(&o0);
        st.y = *reinterpret_cast<float*>(&o1);
        st.z = *reinterpret_cast<float*>(&o2);
        st.w = *reinterpret_cast<float*>(&o3);
        xout[((size_t)s * PSTR4 + node) * 2 + hh] = st;
    }
}

// final 64->3 projection from 4-plane fp16 activations
__global__ __launch_bounds__(256) void proj_kernel(const float4* __restrict__ xc4,
                                                   const float* __restrict__ Wc,
                                                   const float* __restrict__ bc,
                                                   float* __restrict__ out, int n) {
    __shared__ float Wl[192];
    int t = threadIdx.x;
    if (t < 192) Wl[t] = Wc[t];
    __syncthreads();
    int node = blockIdx.x * 256 + t;
    if (node >= n) return;
    float p0 = bc[0], p1 = bc[1], p2 = bc[2];
#pragma unroll
    for (int p = 0; p < 4; ++p) {
#pragma unroll
        for (int hh = 0; hh < 2; ++hh) {
            float4 v = xc4[((size_t)p * PSTR4 + node) * 2 + hh];
            const __half2* q = (const __half2*)&v;
#pragma unroll
            for (int j = 0; j < 4; ++j) {
                float2 f = __half22float2(q[j]);
                int ch = p * 16 + hh * 8 + j * 2;
                p0 += f.x * Wl[ch * 3 + 0] + f.y * Wl[(ch + 1) * 3 + 0];
                p1 += f.x * Wl[ch * 3 + 1] + f.y * Wl[(ch + 1) * 3 + 1];
                p2 += f.x * Wl[ch * 3 + 2] + f.y * Wl[(ch + 1) * 3 + 2];
            }
        }
    }
    out[node * 3 + 0] = p0;
    out[node * 3 + 1] = p1;
    out[node * 3 + 2] = p2;
}

extern "C" void kernel_launch(void* const* d_in, const int* in_sizes, int n_in,
                              void* d_out, int out_size, void* d_ws, size_t ws_size,
                              hipStream_t stream) {
    const float* x  = (const float*)d_in[0];
    const int*   ei = (const int*)d_in[1];
    const float* Ws = (const float*)d_in[2];
    const float* bs = (const float*)d_in[3];
    const float* Wc = (const float*)d_in[4];
    const float* bc = (const float*)d_in[5];
    float* out = (float*)d_out;

    int E = in_sizes[1] / 2;
    const int* src = ei;
    const int* dst = ei + E;
    int nchunks = (E + P1_CHUNK - 1) / P1_CHUNK;

    char* wsb = (char*)d_ws;
    size_t off = 0;
    int*      bcnt    = (int*)(wsb + off); off += 512 * 4;
    int*      boff    = (int*)(wsb + off); off += 512 * 4;
    int*      bcur    = (int*)(wsb + off); off += 512 * 4;
    int*      row_ptr = (int*)(wsb + off); off += 100608 * 4;
    float*    dinv    = (float*)(wsb + off); off += 100352 * 4;
    int*      csr_src = (int*)(wsb + off); off += ((size_t)E + 256) * 4;
    unsigned* ebuf    = (unsigned*)(wsb + off); off += (size_t)E * 4;
    char*     h       = wsb + off; off += (size_t)4 * PSTR4 * 32;  // 4 fp16 planes
    char*     xa      = wsb + off; off += (size_t)4 * PSTR4 * 32;
    char*     xb      = wsb + off; off += (size_t)4 * PSTR4 * 32;

    // graph build
    hipMemsetAsync(bcnt, 0, 512 * sizeof(int), stream);
    hist_kernel<<<nchunks, 256, 0, stream>>>(dst, bcnt, E);
    bscan_kernel<<<1, 512, 0, stream>>>(bcnt, boff, bcur, row_ptr, E, NN);
    p1_kernel<<<nchunks, 256, 0, stream>>>(src, dst, bcur, ebuf, E);
    p2_kernel<<<NB, 256, 0, stream>>>(ebuf, boff, row_ptr, dinv, csr_src, NN);

    // layers (ping-pong 4-plane fp16 xa/xb)
    const void* xin = (const void*)x;
    int xin_half = 0;
    char* bufs[2] = {xa, xb};
    int agg_grid = ((NN + 31) / 32) * 4;   // node-blocks x 4 slices
    for (int l = 0; l < 4; ++l) {
        char* xout = bufs[l & 1];
        mfma_mm_kernel<<<(NN + 63) / 64, 256, 0, stream>>>(
            xin, xin_half, Ws + (size_t)l * HD * HD, dinv, (__half*)h, NN);
        agg_kernel<<<agg_grid, 256, 0, stream>>>(
            (const float4*)h, row_ptr, csr_src, dinv, bs + l * HD,
            (const float4*)xin, (float4*)xout, NN, l > 0);
        xin = (const void*)xout;
        xin_half = 1;
    }
    proj_kernel<<<(NN + 255) / 256, 256, 0, stream>>>((const float4*)bufs[1], Wc, bc, out, NN);
}